// Round 15
// baseline (1886.707 us; speedup 1.0000x reference)
//
#include <hip/hip_runtime.h>

// RGCN block-diagonal layer, f32.
// out = relu( (scatter_sum(msg) * norm) + bias + h @ loop_weight )
// msg[e, b*16+o] = sum_i h[src[e], b*16+i] * W[type[e], b*256 + i*16 + o]
//
// v15: minimize WRITTEN bytes. Session evidence: all streaming writes to
// harness buffers cap at ~930 GB/s (v8-v14: occupancy/width/NT invariant),
// so the 400 MB M intermediate costs 430+ us by itself. This version writes
// only ~115 MB total: LDS-accumulate per 16-dst range (round-3 concept)
// with round-3's latency bugs fixed: coalesced h loads + 32-shfl matvec
// (round-1's verified math), (range,type)-sorted edges so W lives in
// 32 VGPRs per t-segment, 2-deep named-reg prefetch, 6250 even blocks.
// Pipeline:
//   A: init   : out = bias + h @ loop_weight       (LDS-staged LW)
//   Z/H: zero + histogram over key = (dst & ~15) | type   (~N bins)
//   S1/S2/S3: parallel exclusive scan -> row_ptr CSR, cursor
//   C: scatter srec[p] = (src<<4) | (dst & 15)
//   E: edge_lds2 : block = 16 dsts (8 KB LDS acc); 4 waves x 4 types;
//      per edge coalesced h + shfl matvec + LDS f32 atomics; flush =
//      out[d] = relu(out[d] + acc*norm[d])  (non-atomic RMW, fused relu)

__global__ __launch_bounds__(256) void rgcn_init_kernel(
    const float* __restrict__ h, const float* __restrict__ loop_w,
    const float* __restrict__ bias, float* __restrict__ out, int N) {
  __shared__ float lw[128 * 128];  // 64 KB
  for (int idx = threadIdx.x; idx < 128 * 128 / 4; idx += 256) {
    ((float4*)lw)[idx] = ((const float4*)loop_w)[idx];
  }
  __syncthreads();

  const int lane = threadIdx.x & 63;
  const int wid = threadIdx.x >> 6;
  const int group0 = blockIdx.x * 4 + wid;
  const int ngroups = gridDim.x * 4;
  const int totgroups = (N + 3) >> 2;
  const float b0 = bias[lane];
  const float b1 = bias[64 + lane];

  for (int g = group0; g < totgroups; g += ngroups) {
    const int n0 = g * 4;
    const int nn = (N - n0 < 4) ? (N - n0) : 4;
    if (nn == 4) {
      const float* __restrict__ r0 = h + (size_t)n0 * 128;
      const float* __restrict__ r1 = r0 + 128;
      const float* __restrict__ r2 = r1 + 128;
      const float* __restrict__ r3 = r2 + 128;
      float a00 = b0, a01 = b1, a10 = b0, a11 = b1;
      float a20 = b0, a21 = b1, a30 = b0, a31 = b1;
#pragma unroll 4
      for (int k = 0; k < 128; ++k) {
        const float w0 = lw[k * 128 + lane];
        const float w1 = lw[k * 128 + 64 + lane];
        a00 = fmaf(r0[k], w0, a00); a01 = fmaf(r0[k], w1, a01);
        a10 = fmaf(r1[k], w0, a10); a11 = fmaf(r1[k], w1, a11);
        a20 = fmaf(r2[k], w0, a20); a21 = fmaf(r2[k], w1, a21);
        a30 = fmaf(r3[k], w0, a30); a31 = fmaf(r3[k], w1, a31);
      }
      float* __restrict__ o0 = out + (size_t)n0 * 128;
      o0[lane] = a00;        o0[64 + lane] = a01;
      o0[128 + lane] = a10;  o0[192 + lane] = a11;
      o0[256 + lane] = a20;  o0[320 + lane] = a21;
      o0[384 + lane] = a30;  o0[448 + lane] = a31;
    } else {
      for (int r = 0; r < nn; ++r) {
        const int n = n0 + r;
        const float* __restrict__ hr = h + (size_t)n * 128;
        float a0 = b0, a1 = b1;
#pragma unroll 4
        for (int k = 0; k < 128; ++k) {
          const float a = hr[k];
          a0 = fmaf(a, lw[k * 128 + lane], a0);
          a1 = fmaf(a, lw[k * 128 + 64 + lane], a1);
        }
        out[(size_t)n * 128 + lane] = a0;
        out[(size_t)n * 128 + 64 + lane] = a1;
      }
    }
  }
}

__global__ __launch_bounds__(256) void rgcn_zero_kernel(int* __restrict__ p,
                                                        int n) {
  for (int i = blockIdx.x * 256 + threadIdx.x; i < n; i += gridDim.x * 256)
    p[i] = 0;
}

// key = (dst & ~15) | type   (16 types -> key fits in [0, bins))
__global__ __launch_bounds__(256) void rgcn_hist2_kernel(
    const int* __restrict__ edst, const int* __restrict__ etype,
    int* __restrict__ cnt, int E) {
  for (int e = blockIdx.x * 256 + threadIdx.x; e < E; e += gridDim.x * 256) {
    const int key = (edst[e] & ~15) | etype[e];
    atomicAdd(&cnt[key], 1);
  }
}

// ---- parallel exclusive scan over bins (3 kernels) ----
__global__ __launch_bounds__(1024) void rgcn_scan_pass1(
    const int* __restrict__ cnt, int* __restrict__ partial, int bins) {
  __shared__ int sums[1024];
  const int t = threadIdx.x;
  const int base = blockIdx.x * 4096 + t * 4;
  int s = 0;
  if (base + 3 < bins) {
    const int4 v = *(const int4*)(cnt + base);
    s = v.x + v.y + v.z + v.w;
  } else {
    for (int j = 0; j < 4; ++j)
      if (base + j < bins) s += cnt[base + j];
  }
  sums[t] = s;
  __syncthreads();
  for (int off = 512; off > 0; off >>= 1) {
    if (t < off) sums[t] += sums[t + off];
    __syncthreads();
  }
  if (t == 0) partial[blockIdx.x] = sums[0];
}

__global__ __launch_bounds__(1024) void rgcn_scan_pass2(
    int* __restrict__ partial, int nb) {
  __shared__ int sc[1024];
  const int t = threadIdx.x;
  int v[4];
  int s = 0;
#pragma unroll
  for (int j = 0; j < 4; ++j) {
    const int i = t * 4 + j;
    v[j] = (i < nb) ? partial[i] : 0;
    s += v[j];
  }
  sc[t] = s;
  __syncthreads();
#pragma unroll
  for (int off = 1; off < 1024; off <<= 1) {
    const int add = (t >= off) ? sc[t - off] : 0;
    __syncthreads();
    sc[t] += add;
    __syncthreads();
  }
  int run = (t == 0) ? 0 : sc[t - 1];
#pragma unroll
  for (int j = 0; j < 4; ++j) {
    const int i = t * 4 + j;
    if (i < nb) partial[i] = run;
    run += v[j];
  }
}

__global__ __launch_bounds__(1024) void rgcn_scan_pass3(
    const int* __restrict__ cnt, const int* __restrict__ partial,
    int* __restrict__ row_ptr, int* __restrict__ cursor, int bins) {
  __shared__ int sums[1024];
  const int t = threadIdx.x;
  const int base = blockIdx.x * 4096 + t * 4;
  int v0 = 0, v1 = 0, v2 = 0, v3 = 0;
  if (base + 3 < bins) {
    const int4 v = *(const int4*)(cnt + base);
    v0 = v.x; v1 = v.y; v2 = v.z; v3 = v.w;
  } else {
    if (base < bins) v0 = cnt[base];
    if (base + 1 < bins) v1 = cnt[base + 1];
    if (base + 2 < bins) v2 = cnt[base + 2];
  }
  sums[t] = v0 + v1 + v2 + v3;
  __syncthreads();
#pragma unroll
  for (int off = 1; off < 1024; off <<= 1) {
    const int add = (t >= off) ? sums[t - off] : 0;
    __syncthreads();
    sums[t] += add;
    __syncthreads();
  }
  const int run = partial[blockIdx.x] + ((t == 0) ? 0 : sums[t - 1]);
  const int p0 = run, p1 = p0 + v0, p2 = p1 + v1, p3 = p2 + v2;
  if (base + 3 < bins) {
    *(int4*)(row_ptr + base) = make_int4(p0, p1, p2, p3);
    *(int4*)(cursor + base) = make_int4(p0, p1, p2, p3);
  } else {
    if (base < bins) { row_ptr[base] = p0; cursor[base] = p0; }
    if (base + 1 < bins) { row_ptr[base + 1] = p1; cursor[base + 1] = p1; }
    if (base + 2 < bins) { row_ptr[base + 2] = p2; cursor[base + 2] = p2; }
  }
}

__global__ void rgcn_set_kernel(int* __restrict__ p, int v) {
  if (threadIdx.x == 0) *p = v;
}
// -------------------------------------------------------

__global__ __launch_bounds__(256) void rgcn_scatter2_kernel(
    const int* __restrict__ esrc, const int* __restrict__ edst,
    const int* __restrict__ etype, int* __restrict__ cursor,
    int* __restrict__ srec, int E) {
  for (int e = blockIdx.x * 256 + threadIdx.x; e < E; e += gridDim.x * 256) {
    const int d = edst[e];
    const int key = (d & ~15) | etype[e];
    const int p = atomicAdd(&cursor[key], 1);
    srec[p] = (esrc[e] << 4) | (d & 15);
  }
}

// Edge kernel: block = 16-dst range, 8 KB LDS f32 accumulator.
// 4 waves x 4 types; W[t] in 32 VGPRs per t-segment (edges sorted by
// (range,type)). Per edge: coalesced h row (2 dwords/lane), 32-shfl
// block-diag matvec, 2 conflict-free LDS f32 atomics. 2-deep prefetch.
// Flush: out[d] = relu(out[d] + acc*norm[d])  (init supplied bias+loop).
__global__ __launch_bounds__(256) void rgcn_edge_lds2_kernel(
    const float* __restrict__ h, const float* __restrict__ norm,
    const int* __restrict__ srec, const int* __restrict__ row_ptr,
    const float* __restrict__ weight, float* __restrict__ out, int N) {
  __shared__ float acc[16 * 128];  // 8 KB
  const int tid = threadIdx.x;
  const int lane = tid & 63;
  const int w = tid >> 6;  // wave 0..3
  const int b = lane >> 4;
  const int o = lane & 15;
  const int r = blockIdx.x;  // dsts [r*16, r*16+16)

  for (int i = tid; i < 16 * 128 / 4; i += 256)
    ((float4*)acc)[i] = make_float4(0.f, 0.f, 0.f, 0.f);
  __syncthreads();

  for (int tt = 0; tt < 4; ++tt) {
    const int t = w * 4 + tt;
    const int e0 = row_ptr[r * 16 + t];
    const int e1 = row_ptr[r * 16 + t + 1];
    if (e0 == e1) continue;

    const float* __restrict__ wb = weight + t * 2048 + b * 256 + o;
    float wlo[16], whi[16];
#pragma unroll
    for (int i = 0; i < 16; ++i) {
      wlo[i] = wb[i * 16];
      whi[i] = wb[1024 + i * 16];
    }

    // 2-deep software pipeline with named registers (no arrays).
    int recA = srec[e0];
    float loA = h[(size_t)(recA >> 4) * 128 + lane];
    float hiA = h[(size_t)(recA >> 4) * 128 + 64 + lane];

    for (int e = e0; e < e1; ++e) {
      const int rec = recA;
      const float lo = loA, hi = hiA;
      if (e + 1 < e1) {
        recA = srec[e + 1];
        loA = h[(size_t)(recA >> 4) * 128 + lane];
        hiA = h[(size_t)(recA >> 4) * 128 + 64 + lane];
      }
      float m0 = 0.f, m1 = 0.f;
#pragma unroll
      for (int i = 0; i < 16; ++i) {
        m0 = fmaf(__shfl(lo, (lane & 48) + i, 64), wlo[i], m0);
        m1 = fmaf(__shfl(hi, (lane & 48) + i, 64), whi[i], m1);
      }
      const int dl = rec & 15;
      atomicAdd(&acc[dl * 128 + lane], m0);
      atomicAdd(&acc[dl * 128 + 64 + lane], m1);
    }
  }
  __syncthreads();

  // flush: 16 dsts x 32 float4
  for (int idx = tid; idx < 16 * 32; idx += 256) {
    const int dl = idx >> 5;
    const int c4 = idx & 31;
    const int d = r * 16 + dl;
    if (d < N) {
      const float nm = norm[d];
      const float4 a = ((const float4*)acc)[idx];
      float4 ov = ((float4*)out)[(size_t)d * 32 + c4];
      ov.x = fmaxf(fmaf(a.x, nm, ov.x), 0.f);
      ov.y = fmaxf(fmaf(a.y, nm, ov.y), 0.f);
      ov.z = fmaxf(fmaf(a.z, nm, ov.z), 0.f);
      ov.w = fmaxf(fmaf(a.w, nm, ov.w), 0.f);
      ((float4*)out)[(size_t)d * 32 + c4] = ov;
    }
  }
}

// Fallback (ws too small / unexpected shape): unsorted atomic edge kernel.
__global__ __launch_bounds__(256) void rgcn_edge_kernel(
    const float* __restrict__ h, const float* __restrict__ norm,
    const int* __restrict__ esrc, const int* __restrict__ edst,
    const int* __restrict__ etype, const float* __restrict__ weight,
    float* __restrict__ out, int E) {
  const int lane = threadIdx.x & 63;
  const int wid = threadIdx.x >> 6;
  const int wave0 = blockIdx.x * 4 + wid;
  const int nwaves = gridDim.x * 4;
  const int b = lane >> 4;
  const int o = lane & 15;

  for (int e = wave0; e < E; e += nwaves) {
    const int src = esrc[e];
    const int dst = edst[e];
    const int et = etype[e];
    const float s_lo = h[src * 128 + lane];
    const float s_hi = h[src * 128 + 64 + lane];
    const float nrm = norm[dst];
    const float* __restrict__ Wb = weight + et * 2048 + b * 256 + o;
    float m0 = 0.f, m1 = 0.f;
#pragma unroll
    for (int i = 0; i < 16; ++i) {
      const float a_lo = __shfl(s_lo, (lane & 48) + i, 64);
      const float a_hi = __shfl(s_hi, (lane & 48) + i, 64);
      m0 = fmaf(a_lo, Wb[i * 16], m0);
      m1 = fmaf(a_hi, Wb[1024 + i * 16], m1);
    }
    atomicAdd(&out[dst * 128 + lane], m0 * nrm);
    atomicAdd(&out[dst * 128 + 64 + lane], m1 * nrm);
  }
}

__global__ __launch_bounds__(256) void rgcn_relu_kernel(float* __restrict__ out,
                                                        int total4) {
  int i = blockIdx.x * 256 + threadIdx.x;
  const int stride = gridDim.x * 256;
  for (; i < total4; i += stride) {
    float4 v = ((float4*)out)[i];
    v.x = fmaxf(v.x, 0.f);
    v.y = fmaxf(v.y, 0.f);
    v.z = fmaxf(v.z, 0.f);
    v.w = fmaxf(v.w, 0.f);
    ((float4*)out)[i] = v;
  }
}

extern "C" void kernel_launch(void* const* d_in, const int* in_sizes, int n_in,
                              void* d_out, int out_size, void* d_ws, size_t ws_size,
                              hipStream_t stream) {
  const float* h      = (const float*)d_in[0];
  const float* norm   = (const float*)d_in[1];
  const int*   esrc   = (const int*)d_in[2];
  const int*   edst   = (const int*)d_in[3];
  const int*   etype  = (const int*)d_in[4];
  const float* weight = (const float*)d_in[5];
  const float* bias   = (const float*)d_in[6];
  const float* loop_w = (const float*)d_in[7];
  float* out = (float*)d_out;

  const int N = in_sizes[0] / 128;
  const int E = in_sizes[2];
  const int nrels = in_sizes[5] / 2048;

  rgcn_init_kernel<<<2048, 256, 0, stream>>>(h, loop_w, bias, out, N);

  const int nR = (N + 15) >> 4;       // 16-dst ranges
  const int bins = nR * 16;           // ~N bins
  // ws (dwords): cnt[bins] | row_ptr[bins+1 pad4] | cursor[bins] |
  //              partial[4096] | srec[E]
  const size_t o_rp = ((size_t)bins + 3) & ~(size_t)3;
  const size_t o_cur = (o_rp + bins + 1 + 3) & ~(size_t)3;
  const size_t o_part = (o_cur + bins + 3) & ~(size_t)3;
  const size_t o_srec = o_part + 4096;
  const size_t need = (o_srec + (size_t)E) * 4;
  const int nb = (bins + 4095) / 4096;

  if (nrels == 16 && N >= 1 && N < (1 << 26) && nb <= 4096 &&
      ws_size >= need) {
    int* base    = (int*)d_ws;
    int* cnt     = base;
    int* row_ptr = base + o_rp;
    int* cursor  = base + o_cur;
    int* partial = base + o_part;
    int* srec    = base + o_srec;

    rgcn_zero_kernel<<<256, 256, 0, stream>>>(cnt, bins);
    rgcn_hist2_kernel<<<2048, 256, 0, stream>>>(edst, etype, cnt, E);
    rgcn_scan_pass1<<<nb, 1024, 0, stream>>>(cnt, partial, bins);
    rgcn_scan_pass2<<<1, 1024, 0, stream>>>(partial, nb);
    rgcn_scan_pass3<<<nb, 1024, 0, stream>>>(cnt, partial, row_ptr, cursor,
                                             bins);
    rgcn_set_kernel<<<1, 64, 0, stream>>>(row_ptr + bins, E);
    rgcn_scatter2_kernel<<<2048, 256, 0, stream>>>(esrc, edst, etype, cursor,
                                                   srec, E);
    rgcn_edge_lds2_kernel<<<nR, 256, 0, stream>>>(h, norm, srec, row_ptr,
                                                  weight, out, N);
  } else {
    rgcn_edge_kernel<<<4096, 256, 0, stream>>>(h, norm, esrc, edst, etype,
                                               weight, out, E);
    rgcn_relu_kernel<<<2048, 256, 0, stream>>>(out, (N * 128) / 4);
  }
}